// Round 2
// baseline (1331.740 us; speedup 1.0000x reference)
//
#include <hip/hip_runtime.h>

#define NEGV -1e30f
static constexpr int BATCH = 64;
static constexpr int NN = 512;
static constexpr int MM = 512;
static constexpr int NM = NN * MM;
static constexpr size_t TOTAL = (size_t)BATCH * NM;

// ---------------------------------------------------------------------------
// K1: wavefront DP, one 64-lane wave per (batch, direction) problem.
// Lane t owns rows [8t, 8t+8). Diagonal state (k-1, k-2) lives in registers;
// the only cross-lane dependency is lane t-1's row-7 values -> __shfl_up.
// No LDS, no __syncthreads. k-loop unrolled x4 so (j&3) is compile-time
// (i0 = 8*lane is 0 mod 4), keeping store-staging arrays in VGPRs.
// ---------------------------------------------------------------------------
__global__ __launch_bounds__(64) void dp_kernel(const float* __restrict__ D,
                                                float* __restrict__ Rf,
                                                float* __restrict__ Rb) {
    const int blk = blockIdx.x;
    const int b = blk & (BATCH - 1);
    const int dir = blk >> 6;                 // wave-uniform (SGPR)
    const float* __restrict__ Db = D + (size_t)b * NM;
    float* __restrict__ R = (dir ? Rb : Rf) + (size_t)b * NM;
    const int lane = threadIdx.x;             // 0..63
    const int i0 = lane * 8;

    float p1[8], p2[8];      // R on diagonals k-1 / k-2 for my 8 rows
    float dv[8], dnx[8];     // D for diag k (current) and k+1 (prefetch)
    float stv[8][4];         // store staging: 4-column groups per row

#pragma unroll
    for (int r = 0; r < 8; ++r) {
        p1[r] = NEGV; p2[r] = NEGV; dnx[r] = 0.f;
#pragma unroll
        for (int c = 0; c < 4; ++c) stv[r][c] = 0.f;
    }
    // prefetch diag k=0 (only cell (0,0) is valid)
    if (lane == 0) dnx[0] = Db[dir ? (NM - 1) : 0];

    for (int kb = 0; kb < NN + MM; kb += 4) {
#pragma unroll
        for (int kk = 0; kk < 4; ++kk) {
            const int k = kb + kk;

            // current-diag D values
#pragma unroll
            for (int r = 0; r < 8; ++r) dv[r] = dnx[r];
            // prefetch next diag's D (8 independent scalar loads, used next iter)
#pragma unroll
            for (int r = 0; r < 8; ++r) {
                const int i = i0 + r;
                const int jn = k + 1 - i;
                if (jn >= 0 && jn < MM) {
                    int idx = i * MM + jn;
                    if (dir) idx = NM - 1 - idx;
                    dnx[r] = Db[idx];
                }
            }

            // boundary values from lane-1's last row (diag k-1 and k-2)
            const float up_s = __shfl_up(p1[7], 1);
            const float dg_s = __shfl_up(p2[7], 1);
            const float up0 = (lane == 0) ? NEGV : up_s;
            const float dg0 = (lane == 0) ? NEGV : dg_s;

            float np[8];
#pragma unroll
            for (int r = 0; r < 8; ++r) {
                const int i = i0 + r;
                const int j = k - i;
                float val = NEGV;
                if (j >= 0 && j < MM) {
                    const float upsrc = (r == 0) ? up0 : p1[r - 1];
                    const float dgsrc = (r == 0) ? dg0 : p2[r - 1];
                    const float dg = (i == 0) ? ((j == 0) ? 0.f : NEGV)
                                              : ((j == 0) ? NEGV : dgsrc);
                    const float up = (i == 0) ? NEGV : upsrc;
                    const float lf = (j == 0) ? NEGV : p1[r];
                    const float m = fmaxf(fmaxf(dg, up), lf);
                    // one arg equals m -> log argument in [1,3]
                    val = dv[r] + m +
                        __logf(__expf(dg - m) + __expf(up - m) + __expf(lf - m));
                    // (k - i) & 3 == (k - r) & 3: compile-time after unroll
                    stv[r][(k - i0 - r) & 3] = val;
                    if (((k - i0 - r) & 3) == 3) {
                        // full 4-column group -> one aligned float4 store
                        if (dir) {
                            float4 v = make_float4(stv[r][3], stv[r][2],
                                                   stv[r][1], stv[r][0]);
                            *(float4*)(R + (NM - 1 - i * MM - j)) = v;
                        } else {
                            float4 v = make_float4(stv[r][0], stv[r][1],
                                                   stv[r][2], stv[r][3]);
                            *(float4*)(R + (i * MM + j - 3)) = v;
                        }
                    }
                }
                np[r] = val;
            }
#pragma unroll
            for (int r = 0; r < 8; ++r) { p2[r] = p1[r]; p1[r] = np[r]; }
        }
    }
}

// ---------------------------------------------------------------------------
// block-level max reduction (256 threads)
// ---------------------------------------------------------------------------
__device__ inline float blockMax256(float v) {
    __shared__ float sm[256];
    sm[threadIdx.x] = v;
    __syncthreads();
    for (int s = 128; s > 0; s >>= 1) {
        if ((int)threadIdx.x < s)
            sm[threadIdx.x] = fmaxf(sm[threadIdx.x], sm[threadIdx.x + s]);
        __syncthreads();
    }
    return sm[0];
}

// K2: logit = f + b - d (in place into out, which holds f), per-block max
__global__ __launch_bounds__(256) void logit_kernel(const float4* __restrict__ D,
                                                    const float4* __restrict__ Rb,
                                                    float4* __restrict__ out,
                                                    float* __restrict__ partial) {
    const size_t n4 = TOTAL / 4;
    float mx = NEGV;
    const size_t stride = (size_t)gridDim.x * blockDim.x;
    for (size_t idx = (size_t)blockIdx.x * blockDim.x + threadIdx.x; idx < n4;
         idx += stride) {
        float4 f = out[idx], bb = Rb[idx], d = D[idx];
        float4 v = make_float4(f.x + bb.x - d.x, f.y + bb.y - d.y,
                               f.z + bb.z - d.z, f.w + bb.w - d.w);
        out[idx] = v;
        mx = fmaxf(mx, fmaxf(fmaxf(v.x, v.y), fmaxf(v.z, v.w)));
    }
    float bm = blockMax256(mx);
    if (threadIdx.x == 0) partial[blockIdx.x] = bm;
}

// K3: reduce partials to one scalar
__global__ __launch_bounds__(256) void finalmax_kernel(const float* __restrict__ partial,
                                                       int n,
                                                       float* __restrict__ outmax) {
    float mx = NEGV;
    for (int i = threadIdx.x; i < n; i += 256) mx = fmaxf(mx, partial[i]);
    float bm = blockMax256(mx);
    if (threadIdx.x == 0) *outmax = bm;
}

// K4: out -= max  (GAMMA = T = 1)
__global__ __launch_bounds__(256) void sub_kernel(float4* __restrict__ out,
                                                  const float* __restrict__ maxp) {
    const float mx = *maxp;
    const size_t n4 = TOTAL / 4;
    const size_t stride = (size_t)gridDim.x * blockDim.x;
    for (size_t idx = (size_t)blockIdx.x * blockDim.x + threadIdx.x; idx < n4;
         idx += stride) {
        float4 v = out[idx];
        v.x -= mx; v.y -= mx; v.z -= mx; v.w -= mx;
        out[idx] = v;
    }
}

extern "C" void kernel_launch(void* const* d_in, const int* in_sizes, int n_in,
                              void* d_out, int out_size, void* d_ws, size_t ws_size,
                              hipStream_t stream) {
    const float* D = (const float*)d_in[0];
    float* out = (float*)d_out;      // holds Rf after K1, logit after K2
    float* Rb = (float*)d_ws;        // 64 MB backward DP result
    float* partial = Rb + TOTAL;     // 2048 floats
    float* maxp = partial + 2048;    // 1 float

    dp_kernel<<<128, 64, 0, stream>>>(D, out, Rb);
    logit_kernel<<<2048, 256, 0, stream>>>((const float4*)D, (const float4*)Rb,
                                           (float4*)out, partial);
    finalmax_kernel<<<1, 256, 0, stream>>>(partial, 2048, maxp);
    sub_kernel<<<2048, 256, 0, stream>>>((float4*)out, maxp);
}